// Round 4
// baseline (613.844 us; speedup 1.0000x reference)
//
#include <hip/hip_runtime.h>

#define WS_ALIGN(x) (((x) + size_t(255)) & ~size_t(255))

typedef unsigned int uint;
typedef unsigned short ushort;

__device__ __forceinline__ ushort f2bf(float f) {
    uint u = __float_as_uint(f);
    return (ushort)((u + 0x7fff + ((u >> 16) & 1)) >> 16);  // RNE
}
__device__ __forceinline__ float bflo(uint u) { return __uint_as_float(u << 16); }
__device__ __forceinline__ float bfhi(uint u) { return __uint_as_float(u & 0xffff0000u); }
__device__ __forceinline__ float bf1(ushort s) { return __uint_as_float(((uint)s) << 16); }

// ---------------- CSR build ----------------

__global__ void count_kernel(const int* __restrict__ dst, int E, int* __restrict__ deg) {
    int i = blockIdx.x * blockDim.x + threadIdx.x;
    int S = gridDim.x * blockDim.x;
    int d0 = (i + 0 * S < E) ? dst[i + 0 * S] : -1;
    int d1 = (i + 1 * S < E) ? dst[i + 1 * S] : -1;
    int d2 = (i + 2 * S < E) ? dst[i + 2 * S] : -1;
    int d3 = (i + 3 * S < E) ? dst[i + 3 * S] : -1;
    if (d0 >= 0) atomicAdd(&deg[d0], 1);
    if (d1 >= 0) atomicAdd(&deg[d1], 1);
    if (d2 >= 0) atomicAdd(&deg[d2], 1);
    if (d3 >= 0) atomicAdd(&deg[d3], 1);
}

__global__ __launch_bounds__(1024) void scan_part(const int* __restrict__ deg,
                                                  int* __restrict__ roff,
                                                  int* __restrict__ partials,
                                                  float* __restrict__ dinv, int N) {
    __shared__ int lds[1024];
    int tid = threadIdx.x;
    int g = blockIdx.x * 1024 + tid;
    int v = (g < N) ? deg[g] : 0;
    if (g < N) dinv[g] = rsqrtf((float)(v + 1));  // +1 self-loop
    lds[tid] = v;
    __syncthreads();
    for (int off = 1; off < 1024; off <<= 1) {
        int t = (tid >= off) ? lds[tid - off] : 0;
        __syncthreads();
        if (tid >= off) lds[tid] += t;
        __syncthreads();
    }
    if (g < N) roff[g] = lds[tid] - v;  // exclusive
    if (tid == 1023) partials[blockIdx.x] = lds[1023];
}

__global__ void scan_tot(int* __restrict__ partials, int n) {
    __shared__ int lds[128];
    int tid = threadIdx.x;
    int v = (tid < n) ? partials[tid] : 0;
    lds[tid] = v;
    __syncthreads();
    for (int off = 1; off < 128; off <<= 1) {
        int t = (tid >= off) ? lds[tid - off] : 0;
        __syncthreads();
        if (tid >= off) lds[tid] += t;
        __syncthreads();
    }
    if (tid < n) partials[tid] = lds[tid] - v;  // exclusive over chunks
}

__global__ void scan_add(int* __restrict__ roff, const int* __restrict__ partials,
                         int N, int Etot) {
    int i = blockIdx.x * blockDim.x + threadIdx.x;
    if (i < N) roff[i] += partials[i >> 10];
    if (i == 0) roff[N] = Etot;
}

// 4 edges per thread (grid-strided) -> 4 independent atomic->store chains
__global__ void scatter_kernel(const int* __restrict__ src, const int* __restrict__ dst,
                               int E, const int* __restrict__ roff, int* __restrict__ cursor,
                               int* __restrict__ esrc) {
    int i = blockIdx.x * blockDim.x + threadIdx.x;
    int S = gridDim.x * blockDim.x;
    int s[4], d[4];
    bool ok[4];
#pragma unroll
    for (int k = 0; k < 4; ++k) {
        int e = i + k * S;
        ok[k] = e < E;
        s[k] = ok[k] ? src[e] : 0;
        d[k] = ok[k] ? dst[e] : 0;
    }
    int base[4];
#pragma unroll
    for (int k = 0; k < 4; ++k) base[k] = ok[k] ? roff[d[k]] : 0;
    int pos[4];
#pragma unroll
    for (int k = 0; k < 4; ++k) pos[k] = ok[k] ? atomicAdd(&cursor[d[k]], 1) : 0;
#pragma unroll
    for (int k = 0; k < 4; ++k)
        if (ok[k]) esrc[base[k] + pos[k]] = s[k];
}

// ---------------- GEMM (K=128 fixed), optional fused BN+ReLU on A ----------------
// Epilogue: multiply row by dinv[row], emit bf16 (hs = dinv * h).

template <int TN, bool BN>
__global__ __launch_bounds__(256) void gemm_k128(const float* __restrict__ A,
                                                 const float* __restrict__ W,
                                                 const float* __restrict__ scale,
                                                 const float* __restrict__ shift,
                                                 const float* __restrict__ dinv,
                                                 ushort* __restrict__ Cb, int M) {
    constexpr int TM = 64, KC = 32;
    constexpr int CPT = TN / 16;  // 8 (TN=128) or 4 (TN=64)
    __shared__ float As[KC][TM];   // transposed A tile
    __shared__ float Ws[KC][TN];
    int tid = threadIdx.x;
    int tcol = tid & 15, trow = tid >> 4;
    int r0 = trow * 4, c0 = tcol * CPT;
    int rowBase = blockIdx.x * TM;

    float acc[4][CPT];
#pragma unroll
    for (int i = 0; i < 4; ++i)
#pragma unroll
        for (int j = 0; j < CPT; ++j) acc[i][j] = 0.f;

    for (int kc = 0; kc < 128; kc += KC) {
#pragma unroll
        for (int l = tid; l < TM * KC / 4; l += 256) {
            int r = l >> 3;
            int kf = (l & 7) << 2;
            int grow = rowBase + r;
            float4 v = make_float4(0.f, 0.f, 0.f, 0.f);
            if (grow < M) v = *(const float4*)&A[(size_t)grow * 128 + kc + kf];
            if (BN) {
                int k = kc + kf;
                v.x = fmaxf(fmaf(v.x, scale[k + 0], shift[k + 0]), 0.f);
                v.y = fmaxf(fmaf(v.y, scale[k + 1], shift[k + 1]), 0.f);
                v.z = fmaxf(fmaf(v.z, scale[k + 2], shift[k + 2]), 0.f);
                v.w = fmaxf(fmaf(v.w, scale[k + 3], shift[k + 3]), 0.f);
            }
            As[kf + 0][r] = v.x;
            As[kf + 1][r] = v.y;
            As[kf + 2][r] = v.z;
            As[kf + 3][r] = v.w;
        }
#pragma unroll
        for (int l = tid; l < KC * TN / 4; l += 256) {
            int k = l / (TN / 4);
            int cf = (l % (TN / 4)) * 4;
            *(float4*)&Ws[k][cf] = *(const float4*)&W[(size_t)(kc + k) * TN + cf];
        }
        __syncthreads();
#pragma unroll
        for (int kk = 0; kk < KC; ++kk) {
            float4 a4 = *(const float4*)&As[kk][r0];
            float av[4] = {a4.x, a4.y, a4.z, a4.w};
            float bv[CPT];
#pragma unroll
            for (int j = 0; j < CPT; j += 4) {
                float4 b4 = *(const float4*)&Ws[kk][c0 + j];
                bv[j] = b4.x; bv[j + 1] = b4.y; bv[j + 2] = b4.z; bv[j + 3] = b4.w;
            }
#pragma unroll
            for (int i = 0; i < 4; ++i)
#pragma unroll
                for (int j = 0; j < CPT; ++j) acc[i][j] = fmaf(av[i], bv[j], acc[i][j]);
        }
        __syncthreads();
    }
#pragma unroll
    for (int i = 0; i < 4; ++i) {
        int gr = rowBase + r0 + i;
        if (gr < M) {
            float dv = dinv[gr];
            uint p[CPT / 2];
#pragma unroll
            for (int j = 0; j < CPT; j += 2)
                p[j / 2] = (uint)f2bf(acc[i][j] * dv) | ((uint)f2bf(acc[i][j + 1] * dv) << 16);
            uint* dst = (uint*)&Cb[(size_t)gr * TN + c0];
#pragma unroll
            for (int j = 0; j < CPT / 2; ++j) dst[j] = p[j];
        }
    }
}

// ---------------- SpMM: unweighted gather-sum of hs rows, scale by dinv ----

__global__ __launch_bounds__(256) void spmm128(const ushort* __restrict__ hb,
                                               const int* __restrict__ roff,
                                               const int* __restrict__ esrc,
                                               const float* __restrict__ dinv,
                                               float* __restrict__ out, int N) {
    int node = blockIdx.x * 4 + (threadIdx.x >> 6);
    if (node >= N) return;
    int lane = threadIdx.x & 63;
    const uint* hp = (const uint*)hb;  // 2 bf16 per uint, row = 64 uints
    uint sv = hp[(size_t)node * 64 + lane];
    float ax = bflo(sv), ay = bfhi(sv);  // self contribution hs[v]
    float bx = 0.f, by = 0.f;
    int e0 = roff[node], e1 = roff[node + 1];
    int e = e0;
    for (; e + 8 <= e1; e += 8) {
        int s[8];
        uint u[8];
#pragma unroll
        for (int j = 0; j < 8; ++j) s[j] = esrc[e + j];
#pragma unroll
        for (int j = 0; j < 8; ++j) u[j] = hp[(size_t)s[j] * 64 + lane];
#pragma unroll
        for (int j = 0; j < 8; ++j) {
            if (j & 1) { bx += bflo(u[j]); by += bfhi(u[j]); }
            else       { ax += bflo(u[j]); ay += bfhi(u[j]); }
        }
    }
    for (; e < e1; ++e) {
        uint u = hp[(size_t)esrc[e] * 64 + lane];
        ax += bflo(u);
        ay += bfhi(u);
    }
    float dv = dinv[node];
    ((float2*)out)[(size_t)node * 64 + lane] =
        make_float2(dv * (ax + bx), dv * (ay + by));
}

__global__ __launch_bounds__(256) void spmm64(const ushort* __restrict__ hb,
                                              const int* __restrict__ roff,
                                              const int* __restrict__ esrc,
                                              const float* __restrict__ dinv,
                                              float* __restrict__ out, int N) {
    int node = blockIdx.x * 4 + (threadIdx.x >> 6);
    if (node >= N) return;
    int lane = threadIdx.x & 63;
    float acc = bf1(hb[(size_t)node * 64 + lane]);  // self
    float acc2 = 0.f;
    int e0 = roff[node], e1 = roff[node + 1];
    int e = e0;
    for (; e + 8 <= e1; e += 8) {
        int s[8];
        ushort u[8];
#pragma unroll
        for (int j = 0; j < 8; ++j) s[j] = esrc[e + j];
#pragma unroll
        for (int j = 0; j < 8; ++j) u[j] = hb[(size_t)s[j] * 64 + lane];
#pragma unroll
        for (int j = 0; j < 8; ++j) {
            if (j & 1) acc2 += bf1(u[j]);
            else       acc  += bf1(u[j]);
        }
    }
    for (; e < e1; ++e) acc += bf1(hb[(size_t)esrc[e] * 64 + lane]);
    out[(size_t)node * 64 + lane] = dinv[node] * (acc + acc2);
}

// ---------------- BatchNorm stats / apply ----------------

__global__ __launch_bounds__(256) void col_reduce(const float* __restrict__ a, int M, int F,
                                                  float* __restrict__ sums) {
    int c = threadIdx.x % F;
    int rpi = 256 / F;
    int rsub = threadIdx.x / F;
    float s = 0.f, q = 0.f;
    for (int r = blockIdx.x * rpi + rsub; r < M; r += gridDim.x * rpi) {
        float v = a[(size_t)r * F + c];
        s += v;
        q += v * v;
    }
    __shared__ float ls[256], lq[256];
    ls[threadIdx.x] = s;
    lq[threadIdx.x] = q;
    __syncthreads();
    if (threadIdx.x < F) {
        for (int t = threadIdx.x + F; t < 256; t += F) {
            s += ls[t];
            q += lq[t];
        }
        atomicAdd(&sums[c], s);
        atomicAdd(&sums[F + c], q);
    }
}

__global__ void bn_final(const float* __restrict__ sums, const float* __restrict__ gamma,
                         const float* __restrict__ beta, int M, int F,
                         float* __restrict__ scale, float* __restrict__ shift) {
    int c = threadIdx.x;
    if (c >= F) return;
    float mean = sums[c] / (float)M;
    float var = sums[F + c] / (float)M - mean * mean;
    float iv = rsqrtf(var + 1e-5f);
    float sc = gamma[c] * iv;
    scale[c] = sc;
    shift[c] = beta[c] - mean * sc;
}

__global__ void apply_bn64(const float* __restrict__ a, const float* __restrict__ scale,
                           const float* __restrict__ shift, float* __restrict__ out, int n4) {
    int i = blockIdx.x * blockDim.x + threadIdx.x;
    if (i >= n4) return;
    float4 v = ((const float4*)a)[i];
    int c0 = (i & 15) * 4;  // F=64 -> 16 float4 per row
    float4 sc = *(const float4*)&scale[c0];
    float4 sh = *(const float4*)&shift[c0];
    v.x = fmaf(v.x, sc.x, sh.x);
    v.y = fmaf(v.y, sc.y, sh.y);
    v.z = fmaf(v.z, sc.z, sh.z);
    v.w = fmaf(v.w, sc.w, sh.w);
    ((float4*)out)[i] = v;
}

// ---------------- launch ----------------

extern "C" void kernel_launch(void* const* d_in, const int* in_sizes, int n_in,
                              void* d_out, int out_size, void* d_ws, size_t ws_size,
                              hipStream_t stream) {
    const float* x      = (const float*)d_in[0];
    const float* W1     = (const float*)d_in[1];
    const float* gamma1 = (const float*)d_in[3];
    const float* beta1  = (const float*)d_in[4];
    const float* W2     = (const float*)d_in[5];
    const float* gamma2 = (const float*)d_in[7];
    const float* beta2  = (const float*)d_in[8];
    const int*   ei     = (const int*)d_in[9];

    const int hid  = in_sizes[2];            // 128
    const int outc = in_sizes[6];            // 64
    const int inc  = in_sizes[1] / hid;      // 128
    const int N    = in_sizes[0] / inc;      // 100000
    const int E    = in_sizes[9] / 2;        // 1600000
    const int* srcp = ei;
    const int* dstp = ei + E;

    char* wsp = (char*)d_ws;
    size_t off = 0;
    auto alloc = [&](size_t bytes) -> void* {
        void* p = wsp + off;
        off += WS_ALIGN(bytes);
        return p;
    };
    // zeroed region first
    int*   deg    = (int*)alloc((size_t)N * 4);
    int*   cursor = (int*)alloc((size_t)N * 4);
    float* sums1  = (float*)alloc((size_t)2 * hid * 4);
    float* sums2  = (float*)alloc((size_t)2 * outc * 4);
    size_t zeroBytes = off;
    // rest
    int*   roff     = (int*)alloc((size_t)(N + 1) * 4);
    float* dinv     = (float*)alloc((size_t)N * 4);
    int    nchunks  = (N + 1023) / 1024;
    int*   partials = (int*)alloc((size_t)nchunks * 4);
    float* scale1   = (float*)alloc((size_t)hid * 4);
    float* shift1   = (float*)alloc((size_t)hid * 4);
    float* scale2   = (float*)alloc((size_t)outc * 4);
    float* shift2   = (float*)alloc((size_t)outc * 4);
    int*   esrc     = (int*)alloc((size_t)E * 4);
    ushort* h1b     = (ushort*)alloc((size_t)N * hid * 2);   // bf16 hs1
    float* agg1     = (float*)alloc((size_t)N * hid * 4);
    ushort* h2b     = h1b;          // h1b dead after spmm128
    float* agg2     = agg1;         // agg1 dead after gemm2 reads it

    hipMemsetAsync(d_ws, 0, zeroBytes, stream);

    int qthreads = (E + 3) / 4;
    count_kernel<<<(qthreads + 255) / 256, 256, 0, stream>>>(dstp, E, deg);
    scan_part<<<nchunks, 1024, 0, stream>>>(deg, roff, partials, dinv, N);
    scan_tot<<<1, 128, 0, stream>>>(partials, nchunks);
    scan_add<<<(N + 255) / 256, 256, 0, stream>>>(roff, partials, N, E);
    scatter_kernel<<<(qthreads + 255) / 256, 256, 0, stream>>>(srcp, dstp, E, roff, cursor, esrc);

    // layer 1: hs1 = dinv * (x @ W1) (bf16) ; agg1 = dinv * (self + gather-sum) ; BN1
    gemm_k128<128, false><<<(N + 63) / 64, 256, 0, stream>>>(x, W1, nullptr, nullptr, dinv, h1b, N);
    spmm128<<<(N + 3) / 4, 256, 0, stream>>>(h1b, roff, esrc, dinv, agg1, N);
    col_reduce<<<256, 256, 0, stream>>>(agg1, N, 128, sums1);
    bn_final<<<1, 128, 0, stream>>>(sums1, gamma1, beta1, N, 128, scale1, shift1);

    // layer 2
    gemm_k128<64, true><<<(N + 63) / 64, 256, 0, stream>>>(agg1, W2, scale1, shift1, dinv, h2b, N);
    spmm64<<<(N + 3) / 4, 256, 0, stream>>>(h2b, roff, esrc, dinv, agg2, N);
    col_reduce<<<256, 256, 0, stream>>>(agg2, N, 64, sums2);
    bn_final<<<1, 64, 0, stream>>>(sums2, gamma2, beta2, N, 64, scale2, shift2);
    apply_bn64<<<(N * 64 / 4 + 255) / 256, 256, 0, stream>>>(agg2, scale2, shift2,
                                                             (float*)d_out, N * 64 / 4);
}